// Round 19
// baseline (442.402 us; speedup 1.0000x reference)
//
#include <hip/hip_runtime.h>
#include <hip/hip_bf16.h>

typedef __attribute__((ext_vector_type(8))) short short8;
typedef __attribute__((ext_vector_type(4))) float f32x4;
typedef __attribute__((ext_vector_type(2))) float f32x2;

#define B_T 200
#define B_D 128

typedef const __attribute__((address_space(1))) void gvoid;
typedef __attribute__((address_space(3))) void lvoid;

static __device__ __forceinline__ short f2bf(float f) {
  // round-to-nearest-even f32 -> bf16 (inputs are finite)
  unsigned u = __builtin_bit_cast(unsigned, f);
  u += 0x7fffu + ((u >> 16) & 1u);
  return (short)(u >> 16);
}
static __device__ __forceinline__ short8 cvt8(f32x4 a, f32x4 b) {
  short8 t;
  t[0] = f2bf(a[0]); t[1] = f2bf(a[1]); t[2] = f2bf(a[2]); t[3] = f2bf(a[3]);
  t[4] = f2bf(b[0]); t[5] = f2bf(b[1]); t[6] = f2bf(b[2]); t[7] = f2bf(b[3]);
  return t;
}

// 512 threads / 8 waves. Each wave owns ONE j-column (B-frags = 16 VGPRs);
// x tiles staged f32 via global_load_lds (NO staging VGPRs). Demand ~50 regs
// -> fits the 64-reg budget of (512,8) -> 32 waves/CU (4 blocks) target.
// [R16-R18: reg-staged variants always hit a 48-64 arch-VGPR cap + spill.]
__global__ __launch_bounds__(512, 8)
void ta_fused(const float* __restrict__ x,      // [B,T,D]
              const float* __restrict__ cand,   // [B,D]
              const void*  __restrict__ maskp,  // [B,T] int32 or 1-byte bool
              const float* __restrict__ W1,     // [384,128]
              const float* __restrict__ b1,     // [128]
              const float* __restrict__ ap,     // [1]
              const float* __restrict__ W2,     // [128]
              const float* __restrict__ b2p,    // [1] (unused: softmax shift-invariant)
              float* __restrict__ out)          // [B,D]
{
  // a_lds: two f32 x-tiles [16][128]. global_load_lds writes LINEAR
  // (base + lane*16); the bank-swizzle is applied on the GLOBAL SOURCE
  // address (unit u of row r holds global unit u^(r&7)) and undone on read.
  __shared__ __align__(16) float a_lds[2][16 * B_D];   // 16 KB
  __shared__ __align__(16) float smem2[8 * 208 + 208]; // sp[8][208] | scores[208]
  __shared__ float red[16];
  float (*sp)[208] = (float (*)[208])smem2;
  float* scores = smem2 + 8 * 208;
  float (*part)[B_D] = (float (*)[B_D])smem2;          // aliases sp (phase C)

  const int b    = blockIdx.x;
  const int tid  = threadIdx.x;
  const int lane = tid & 63;
  const int wv   = tid >> 6;      // 0..7
  const int l15  = lane & 15;
  const int g    = lane >> 4;     // 0..3

  // ---- mask dtype probe (same 512B on every wave -> block-consistent)
  int flag1b;
  {
    const unsigned char* mb = (const unsigned char*)maskp;
    unsigned long long v8 = *(const unsigned long long*)(mb + lane * 8);
    flag1b = __any((v8 & 0xFFFFFF00FFFFFF00ull) != 0ull);
  }
  bool mk = false;
  if (tid < B_T) {
    if (flag1b) mk = ((const unsigned char*)maskp)[(size_t)b * B_T + tid] != 0;
    else        mk = ((const int*)maskp)[(size_t)b * B_T + tid] != 0;
  }

  // ---- STAGE: wave wv moves its 1 KB strip of tile MT (f32, 8 KB total).
  // 16B-unit index off16 = wv*64+lane; r = off16>>5, u = off16&31.
  // LDS linear (base wv*1024 + lane*16); global source pre-swizzled u^(r&7).
  // Tile 12 (rows 192..199): only waves 0..3 (r<8); rows 8..15 stay stale
  // (finite, from tile 10) and are masked in softmax (t>=200).
#define STAGE(MT, BUF) do {                                                   \
    if ((MT) < 12 || wv < 4) {                                                \
      const int off16_ = wv * 64 + lane;                                      \
      const int r_ = off16_ >> 5, u_ = off16_ & 31;                           \
      const float* gp_ = x + ((size_t)b * B_T + (MT) * 16 + r_) * B_D         \
                           + ((u_ ^ (r_ & 7)) << 2);                          \
      __builtin_amdgcn_global_load_lds((gvoid*)gp_,                           \
          (lvoid*)&a_lds[BUF][wv * 256], 16, 0, 0);                           \
    }                                                                         \
  } while (0)

  STAGE(0, 0);
  STAGE(1, 1);

  // ---- phase 1 (register-resident): B-frags + beta for column j0 = wv*16+l15
  const float* cb = cand + (size_t)b * B_D;
  const int j0 = wv * 16 + l15;
  short8 Bf[4];
  #pragma unroll
  for (int ks = 0; ks < 4; ++ks) {
    short8 t;
    #pragma unroll
    for (int e = 0; e < 8; ++e) {
      const int k = ks * 32 + g * 8 + e;
      t[e] = f2bf(fmaf(cb[k], W1[(size_t)(256 + k) * B_D + j0],
                       W1[(size_t)k * B_D + j0]));
    }
    Bf[ks] = t;
  }
  float beta;
  {
    float s = 0.f;
    #pragma unroll 8
    for (int kk = 0; kk < 32; ++kk) {
      const int k = g * 32 + kk;
      s = fmaf(cb[k], W1[(size_t)(B_D + k) * B_D + j0], s);
    }
    s += __shfl_xor(s, 16, 64); s += __shfl_xor(s, 32, 64);
    beta = s + b1[j0];
  }
  const float w2v  = W2[j0];
  const float alpha = ap[0];
  __syncthreads();   // drains global_load_lds: tiles 0,1 ready

  // ---- phase A: 13 tiles, double-buffered; stage mt+2 right after the
  // barrier that frees its buffer. One barrier per tile.
  const int sw = l15 & 7;
  for (int mt = 0; mt < 13; ++mt) {
    const int buf = mt & 1;
    f32x4 acc = {0.f, 0.f, 0.f, 0.f};
    #pragma unroll
    for (int ks = 0; ks < 4; ++ks) {
      const int U0 = ks * 8 + g * 2;
      f32x4 fa = *(const f32x4*)&a_lds[buf][l15 * B_D + (((U0    ) ^ sw) << 2)];
      f32x4 fb = *(const f32x4*)&a_lds[buf][l15 * B_D + (((U0 + 1) ^ sw) << 2)];
      short8 a = cvt8(fa, fb);
      acc = __builtin_amdgcn_mfma_f32_16x16x32_bf16(a, Bf[ks], acc, 0, 0, 0);
    }
    // epilogue: PReLU + W2 on this wave's 16 j's, reduce over l15
    #pragma unroll
    for (int r = 0; r < 4; ++r) {
      float h = acc[r] + beta; h = (h >= 0.f) ? h : alpha * h;
      float v = h * w2v;
      v += __shfl_xor(v, 1, 16); v += __shfl_xor(v, 2, 16);
      v += __shfl_xor(v, 4, 16); v += __shfl_xor(v, 8, 16);
      if (l15 == 0) sp[wv][mt * 16 + g * 4 + r] = v;   // C row = g*4+r
    }
    __syncthreads();              // all waves done with buf; mt+1 committed
    if (mt + 2 < 13) STAGE(mt + 2, buf);   // async into the freed buffer
  }
#undef STAGE

  // ---- phase B: sum the 8 wave partials, masked softmax; scores <- e.
  {
    float s = -INFINITY;
    if (tid < B_T && mk) {
      float t0 = 0.f;
      #pragma unroll
      for (int w = 0; w < 8; ++w) t0 += sp[w][tid];
      s = t0;
    }
    float v = s;
    #pragma unroll
    for (int m = 32; m >= 1; m >>= 1) v = fmaxf(v, __shfl_xor(v, m, 64));
    if (lane == 0) red[wv] = v;
    __syncthreads();
    float mx = -INFINITY;
    #pragma unroll
    for (int i = 0; i < 8; ++i) mx = fmaxf(mx, red[i]);
    float e = (tid < B_T && mk) ? __expf(s - mx) : 0.f;
    float sv = e;
    #pragma unroll
    for (int m = 32; m >= 1; m >>= 1) sv += __shfl_xor(sv, m, 64);
    if (lane == 0) red[8 + wv] = sv;
    if (tid < 208) scores[tid] = e;   // t in [200,208): e==0
    __syncthreads();                  // sp dead after this -> part alias OK
  }

  // ---- phase C: part[wv][:] = sum_{t in wv-slice} e[t]*x[t,:] (L2/L3-hot).
  {
    const int d2 = lane * 2;
    const float* xc = x + ((size_t)b * B_T + wv * 25) * B_D + d2;
    f32x2 acc0 = {0.f, 0.f}, acc1 = {0.f, 0.f};
    #pragma unroll
    for (int t = 0; t < 24; t += 2) {
      f32x2 xv0 = *(const f32x2*)(xc + (size_t)t * B_D);
      f32x2 xv1 = *(const f32x2*)(xc + (size_t)(t + 1) * B_D);
      float w0 = scores[wv * 25 + t];
      float w1 = scores[wv * 25 + t + 1];
      acc0[0] = fmaf(w0, xv0[0], acc0[0]); acc1[0] = fmaf(w1, xv1[0], acc1[0]);
      acc0[1] = fmaf(w0, xv0[1], acc0[1]); acc1[1] = fmaf(w1, xv1[1], acc1[1]);
    }
    {
      f32x2 xv = *(const f32x2*)(xc + (size_t)24 * B_D);
      float w = scores[wv * 25 + 24];
      acc0[0] = fmaf(w, xv[0], acc0[0]); acc0[1] = fmaf(w, xv[1], acc0[1]);
    }
    acc0[0] += acc1[0]; acc0[1] += acc1[1];
    *(f32x2*)&part[wv][d2] = acc0;
  }
  __syncthreads();
  if (tid < B_D) {
    float Z = 0.f;
    #pragma unroll
    for (int i = 0; i < 8; ++i) Z += red[8 + i];
    float s = 0.f;
    #pragma unroll
    for (int p = 0; p < 8; ++p) s += part[p][tid];
    out[(size_t)b * B_D + tid] = s / Z;
  }
}

extern "C" void kernel_launch(void* const* d_in, const int* in_sizes, int n_in,
                              void* d_out, int out_size, void* d_ws, size_t ws_size,
                              hipStream_t stream) {
  const float* x    = (const float*)d_in[0];
  const float* cand = (const float*)d_in[1];
  const void*  mask = d_in[2];
  const float* W1   = (const float*)d_in[3];
  const float* b1   = (const float*)d_in[4];
  const float* a    = (const float*)d_in[5];
  const float* W2   = (const float*)d_in[6];
  const float* b2   = (const float*)d_in[7];
  float* out = (float*)d_out;
  const int B = in_sizes[1] / B_D;   // candidate is [B,128]
  ta_fused<<<B, 512, 0, stream>>>(x, cand, mask, W1, b1, a, W2, b2, out);
}

// Round 20
// 272.976 us; speedup vs baseline: 1.6207x; 1.6207x over previous
//
#include <hip/hip_runtime.h>
#include <hip/hip_bf16.h>

typedef __attribute__((ext_vector_type(8))) short short8;
typedef __attribute__((ext_vector_type(4))) float f32x4;
typedef __attribute__((ext_vector_type(2))) float f32x2;

#define B_T 200
#define B_D 128

static __device__ __forceinline__ short f2bf(float f) {
  // round-to-nearest-even f32 -> bf16 (inputs are finite)
  unsigned u = __builtin_bit_cast(unsigned, f);
  u += 0x7fffu + ((u >> 16) & 1u);
  return (short)(u >> 16);
}
static __device__ __forceinline__ float bf2f_lo(unsigned u) {
  return __builtin_bit_cast(float, u << 16);
}
static __device__ __forceinline__ float bf2f_hi(unsigned u) {
  return __builtin_bit_cast(float, u & 0xffff0000u);
}
static __device__ __forceinline__ short8 cvt8(f32x4 a, f32x4 b) {
  short8 t;
  t[0] = f2bf(a[0]); t[1] = f2bf(a[1]); t[2] = f2bf(a[2]); t[3] = f2bf(a[3]);
  t[4] = f2bf(b[0]); t[5] = f2bf(b[1]); t[6] = f2bf(b[2]); t[7] = f2bf(b[3]);
  return t;
}

// 512 threads / 8 waves, (512,4): empirically 64-reg budget + 2 blocks/CU
// (R2: identical config, VGPR=64, zero spill at ~60-reg demand).
// ALL of x staged ONCE as bf16 in LDS (53 KB, XOR-swizzled): phase A reads
// MFMA fragments directly (no per-tile cvt, no per-tile barriers), phase C
// reads LDS instead of L2 (no long-latency chains). x read from HBM once.
__global__ __launch_bounds__(512, 4)
void ta_fused(const float* __restrict__ x,      // [B,T,D]
              const float* __restrict__ cand,   // [B,D]
              const void*  __restrict__ maskp,  // [B,T] int32 or 1-byte bool
              const float* __restrict__ W1,     // [384,128]
              const float* __restrict__ b1,     // [128]
              const float* __restrict__ ap,     // [1]
              const float* __restrict__ W2,     // [128]
              const float* __restrict__ b2p,    // [1] (unused: softmax shift-invariant)
              float* __restrict__ out)          // [B,D]
{
  // x_lds: row r (0..207), 16B-octet o (0..15) at shorts
  // [r*128 + ((o ^ (r&7))<<3)]. Rows 200..207 zeroed (masked in softmax).
  __shared__ __align__(16) short x_lds[208 * B_D];    // 53 KB
  __shared__ __align__(16) float sp[8][208];          // per-wave score partials
  __shared__ float scores[208];
  __shared__ float red[16];
  float (*part)[B_D] = (float (*)[B_D])sp;            // phase-C alias (post-B)

  const int b    = blockIdx.x;
  const int tid  = threadIdx.x;
  const int lane = tid & 63;
  const int wv   = tid >> 6;      // 0..7
  const int l15  = lane & 15;
  const int g    = lane >> 4;     // 0..3

  // ---- stage x: 3200 16B-octets (+128 zero octets for rows 200..207).
  // Coalesced: consecutive tid -> consecutive 32B global. Converts f32->bf16
  // ONCE here; swizzle applied on the LDS write, undone on every read.
  #pragma unroll
  for (int it = 0; it < 7; ++it) {
    const int item = it * 512 + tid;
    if (item < 3200) {
      const int r = item >> 4, o = item & 15;
      const float* gp = x + ((size_t)b * B_T + r) * B_D + o * 8;
      f32x4 v0 = *(const f32x4*)gp;
      f32x4 v1 = *(const f32x4*)(gp + 4);
      *(short8*)&x_lds[r * B_D + ((o ^ (r & 7)) << 3)] = cvt8(v0, v1);
    } else if (item < 3328) {
      const int z = item - 3200;
      const int r = 200 + (z >> 4), o = z & 15;
      short8 zz = {0, 0, 0, 0, 0, 0, 0, 0};
      *(short8*)&x_lds[r * B_D + ((o ^ (r & 7)) << 3)] = zz;
    }
  }

  // ---- mask dtype probe (same 512B on every wave -> block-consistent)
  int flag1b;
  {
    const unsigned char* mb = (const unsigned char*)maskp;
    unsigned long long v8 = *(const unsigned long long*)(mb + lane * 8);
    flag1b = __any((v8 & 0xFFFFFF00FFFFFF00ull) != 0ull);
  }
  bool mk = false;
  if (tid < B_T) {
    if (flag1b) mk = ((const unsigned char*)maskp)[(size_t)b * B_T + tid] != 0;
    else        mk = ((const int*)maskp)[(size_t)b * B_T + tid] != 0;
  }

  // ---- phase 1 (register-resident): B-frags + beta for column j0 = wv*16+l15
  const float* cb = cand + (size_t)b * B_D;
  const int j0 = wv * 16 + l15;
  short8 Bf[4];
  #pragma unroll
  for (int ks = 0; ks < 4; ++ks) {
    short8 t;
    #pragma unroll
    for (int e = 0; e < 8; ++e) {
      const int k = ks * 32 + g * 8 + e;
      t[e] = f2bf(fmaf(cb[k], W1[(size_t)(256 + k) * B_D + j0],
                       W1[(size_t)k * B_D + j0]));
    }
    Bf[ks] = t;
  }
  float beta;
  {
    float s = 0.f;
    #pragma unroll 8
    for (int kk = 0; kk < 32; ++kk) {
      const int k = g * 32 + kk;
      s = fmaf(cb[k], W1[(size_t)(B_D + k) * B_D + j0], s);
    }
    s += __shfl_xor(s, 16, 64); s += __shfl_xor(s, 32, 64);
    beta = s + b1[j0];
  }
  const float w2v  = W2[j0];
  const float alpha = ap[0];
  __syncthreads();   // barrier 1: x_lds fully staged

  // ---- phase A: 13 tiles, NO barriers. Wave wv computes scores' partial
  // for its 16 j's over all rows; fragment row = mt*16 + l15.
  #pragma unroll
  for (int mt = 0; mt < 13; ++mt) {
    const int r = mt * 16 + l15;
    const short* xrow = &x_lds[r * B_D];
    const int sw = r & 7;
    f32x4 acc = {0.f, 0.f, 0.f, 0.f};
    #pragma unroll
    for (int ks = 0; ks < 4; ++ks) {
      short8 a = *(const short8*)&xrow[((ks * 4 + g) ^ sw) << 3];
      acc = __builtin_amdgcn_mfma_f32_16x16x32_bf16(a, Bf[ks], acc, 0, 0, 0);
    }
    #pragma unroll
    for (int rr = 0; rr < 4; ++rr) {
      float h = acc[rr] + beta; h = (h >= 0.f) ? h : alpha * h;
      float v = h * w2v;
      v += __shfl_xor(v, 1, 16); v += __shfl_xor(v, 2, 16);
      v += __shfl_xor(v, 4, 16); v += __shfl_xor(v, 8, 16);
      if (l15 == 0) sp[wv][mt * 16 + g * 4 + rr] = v;   // C row = g*4+rr
    }
  }
  __syncthreads();   // barrier 2

  // ---- phase B: sum the 8 wave partials, masked softmax; scores <- e.
  {
    float s = -INFINITY;
    if (tid < B_T && mk) {
      float t0 = 0.f;
      #pragma unroll
      for (int w = 0; w < 8; ++w) t0 += sp[w][tid];
      s = t0;
    }
    float v = s;
    #pragma unroll
    for (int m = 32; m >= 1; m >>= 1) v = fmaxf(v, __shfl_xor(v, m, 64));
    if (lane == 0) red[wv] = v;
    __syncthreads();   // barrier 3
    float mx = -INFINITY;
    #pragma unroll
    for (int i = 0; i < 8; ++i) mx = fmaxf(mx, red[i]);
    float e = (tid < B_T && mk) ? __expf(s - mx) : 0.f;
    float sv = e;
    #pragma unroll
    for (int m = 32; m >= 1; m >>= 1) sv += __shfl_xor(sv, m, 64);
    if (lane == 0) red[8 + wv] = sv;
    if (tid < 208) scores[tid] = e;   // t in [200,208): e==0
    __syncthreads();   // barrier 4; sp dead -> part alias OK
  }

  // ---- phase C: part[wv][:] = sum_{t in wv-slice} e[t]*x[t,:] from LDS bf16.
  // Lane reads 4B (2 bf16) per t: all 64 lanes within one 256B row -> <=2-way.
  {
    const int o   = lane >> 2;              // octet 0..15
    const int sub = (lane & 3) << 1;        // short offset within octet
    f32x2 acc = {0.f, 0.f};
    #pragma unroll
    for (int t = 0; t < 25; ++t) {
      const int r = wv * 25 + t;
      unsigned u = *(const unsigned*)
          &x_lds[r * B_D + (((o ^ (r & 7)) << 3) + sub)];
      float w = scores[r];
      acc[0] = fmaf(w, bf2f_lo(u), acc[0]);
      acc[1] = fmaf(w, bf2f_hi(u), acc[1]);
    }
    *(f32x2*)&part[wv][lane * 2] = acc;
  }
  __syncthreads();   // barrier 5
  if (tid < B_D) {
    float Z = 0.f;
    #pragma unroll
    for (int i = 0; i < 8; ++i) Z += red[8 + i];
    float s = 0.f;
    #pragma unroll
    for (int p = 0; p < 8; ++p) s += part[p][tid];
    out[(size_t)b * B_D + tid] = s / Z;
  }
}

extern "C" void kernel_launch(void* const* d_in, const int* in_sizes, int n_in,
                              void* d_out, int out_size, void* d_ws, size_t ws_size,
                              hipStream_t stream) {
  const float* x    = (const float*)d_in[0];
  const float* cand = (const float*)d_in[1];
  const void*  mask = d_in[2];
  const float* W1   = (const float*)d_in[3];
  const float* b1   = (const float*)d_in[4];
  const float* a    = (const float*)d_in[5];
  const float* W2   = (const float*)d_in[6];
  const float* b2   = (const float*)d_in[7];
  float* out = (float*)d_out;
  const int B = in_sizes[1] / B_D;   // candidate is [B,128]
  ta_fused<<<B, 512, 0, stream>>>(x, cand, mask, W1, b1, a, W2, b2, out);
}

// Round 22
// 185.761 us; speedup vs baseline: 2.3816x; 1.4695x over previous
//
#include <hip/hip_runtime.h>
#include <hip/hip_bf16.h>

typedef __attribute__((ext_vector_type(8))) short short8;
typedef __attribute__((ext_vector_type(4))) float f32x4;

#define B_T 200
#define B_D 128

static __device__ __forceinline__ short f2bf(float f) {
  // round-to-nearest-even f32 -> bf16 (inputs are finite)
  unsigned u = __builtin_bit_cast(unsigned, f);
  u += 0x7fffu + ((u >> 16) & 1u);
  return (short)(u >> 16);
}
static __device__ __forceinline__ short8 cvt8(f32x4 a, f32x4 b) {
  short8 t;
  t[0] = f2bf(a[0]); t[1] = f2bf(a[1]); t[2] = f2bf(a[2]); t[3] = f2bf(a[3]);
  t[4] = f2bf(b[0]); t[5] = f2bf(b[1]); t[6] = f2bf(b[2]); t[7] = f2bf(b[3]);
  return t;
}

// Kernel 1: block (b, half). half0 = tiles 0..6 (rows 0..111, L=112),
// half1 = tiles 7..12 (rows 112..207, L=96; rows>=200 masked, reads CLAMPED
// to row 199 — R21's OOB crash was half1 phase C reading past x's end).
// Emits partial output O_half[128] (f32) + local softmax state (m, Z) to ws.
__global__ __launch_bounds__(256, 4)
void ta_half(const float* __restrict__ x,      // [B,T,D]
             const float* __restrict__ cand,   // [B,D]
             const void*  __restrict__ maskp,  // [B,T] int32 or 1-byte bool
             const float* __restrict__ W1,     // [384,128]
             const float* __restrict__ b1,     // [128]
             const float* __restrict__ ap,     // [1]
             const float* __restrict__ W2,     // [128]
             float* __restrict__ wsO,          // [B*2,128] partial outputs
             float* __restrict__ wsMZ)         // [B*2,2] (m, Z)
{
  // wbt fragment-linear bf16: element (k,j) at ((k>>3)*128 + j)*8 + (k&7).
  __shared__ __align__(16) short wbt[B_D * B_D];   // 32 KB
  __shared__ float bpart[2][B_D];                  // beta halves
  __shared__ float scores[112];
  __shared__ float red[8];
  float (*part)[B_D] = (float (*)[B_D])wbt;        // phase-C alias (wbt dead)

  const int bi   = blockIdx.x;
  const int b    = bi >> 1;
  const int half = bi & 1;
  const int mt0  = half ? 7 : 0;        // first tile
  const int NT   = half ? 6 : 7;        // tiles in this half
  const int L    = NT * 16;             // local rows (112 or 96)
  const int rbase = mt0 * 16;

  const int tid  = threadIdx.x;
  const int lane = tid & 63;
  const int wv   = tid >> 6;      // 0..3
  const int l15  = lane & 15;
  const int g    = lane >> 4;     // 0..3

  // ---- mask dtype probe (same 512B on every wave -> block-consistent)
  int flag1b;
  {
    const unsigned char* mb = (const unsigned char*)maskp;
    unsigned long long v8 = *(const unsigned long long*)(mb + lane * 8);
    flag1b = __any((v8 & 0xFFFFFF00FFFFFF00ull) != 0ull);
  }
  bool mk = false;
  {
    const int grow = rbase + tid;
    if (tid < L && grow < B_T) {
      if (flag1b) mk = ((const unsigned char*)maskp)[(size_t)b * B_T + grow] != 0;
      else        mk = ((const int*)maskp)[(size_t)b * B_T + grow] != 0;
    }
  }

  // ---- phase 1: Wb = W1a + c (*) W1c -> wbt ; beta halves -> bpart (R9-exact)
  const float* cb = cand + (size_t)b * B_D;
  {
    const int j = tid & 127;
    const int h = tid >> 7;           // 0..1 (wave-uniform)
    #pragma unroll 2
    for (int it = 0; it < 8; ++it) {
      const int ko = it * 2 + h, k0 = ko * 8;
      short8 t;
      #pragma unroll
      for (int e = 0; e < 8; ++e) {
        float c  = cb[k0 + e];
        float wa = W1[(size_t)(k0 + e) * B_D + j];
        float wc = W1[(size_t)(256 + k0 + e) * B_D + j];
        t[e] = f2bf(fmaf(c, wc, wa));
      }
      *(short8*)&wbt[(ko * B_D + j) * 8] = t;   // consecutive-lane 16B write
    }
    float s0 = (h == 0) ? b1[j] : 0.f, s1 = 0.f, s2 = 0.f, s3 = 0.f;
    const float* w1b = W1 + (size_t)(B_D + h * 64) * B_D + j;
    #pragma unroll 8
    for (int k = 0; k < 64; k += 4) {
      s0 = fmaf(cb[h * 64 + k    ], w1b[(size_t)(k    ) * B_D], s0);
      s1 = fmaf(cb[h * 64 + k + 1], w1b[(size_t)(k + 1) * B_D], s1);
      s2 = fmaf(cb[h * 64 + k + 2], w1b[(size_t)(k + 2) * B_D], s2);
      s3 = fmaf(cb[h * 64 + k + 3], w1b[(size_t)(k + 3) * B_D], s3);
    }
    bpart[h][j] = (s0 + s1) + (s2 + s3);
  }
  __syncthreads();   // barrier 1 (only one before MFMA)

  float betaL[8], w2L[8];
  #pragma unroll
  for (int nt = 0; nt < 8; ++nt) {
    int col = nt * 16 + l15;
    betaL[nt] = bpart[0][col] + bpart[1][col];
    w2L[nt]   = W2[col];
  }
  const float alpha = ap[0];

  // ---- phase A: this half's tiles. Wave wv: tiles mt0+wv, mt0+4+wv (if any).
#define TILE_SCORE(MT) do {                                                   \
    int row = (MT) * 16 + l15; if (row > B_T - 1) row = B_T - 1;              \
    const float* xr = x + ((size_t)b * B_T + row) * B_D + g * 8;              \
    f32x4 p0 = *(const f32x4*)(xr +  0), p1 = *(const f32x4*)(xr +   4);      \
    f32x4 p2 = *(const f32x4*)(xr + 32), p3 = *(const f32x4*)(xr +  36);      \
    f32x4 p4 = *(const f32x4*)(xr + 64), p5 = *(const f32x4*)(xr +  68);      \
    f32x4 p6 = *(const f32x4*)(xr + 96), p7 = *(const f32x4*)(xr + 100);      \
    short8 a0 = cvt8(p0, p1), a1 = cvt8(p2, p3);                              \
    short8 a2 = cvt8(p4, p5), a3 = cvt8(p6, p7);                              \
    float sc[4] = {0.f, 0.f, 0.f, 0.f};                                       \
    _Pragma("unroll")                                                         \
    for (int nt = 0; nt < 8; ++nt) {                                          \
      f32x4 acc = {0.f, 0.f, 0.f, 0.f};                                       \
      const short8* wp = (const short8*)wbt + g * B_D + nt * 16 + l15;        \
      acc = __builtin_amdgcn_mfma_f32_16x16x32_bf16(a0, wp[0],    acc, 0,0,0);\
      acc = __builtin_amdgcn_mfma_f32_16x16x32_bf16(a1, wp[512],  acc, 0,0,0);\
      acc = __builtin_amdgcn_mfma_f32_16x16x32_bf16(a2, wp[1024], acc, 0,0,0);\
      acc = __builtin_amdgcn_mfma_f32_16x16x32_bf16(a3, wp[1536], acc, 0,0,0);\
      _Pragma("unroll")                                                       \
      for (int r = 0; r < 4; ++r) {                                           \
        float h_ = acc[r] + betaL[nt];                                        \
        float p_ = (h_ >= 0.f) ? h_ : alpha * h_;                             \
        sc[r] += p_ * w2L[nt];                                                \
      }                                                                       \
    }                                                                         \
    _Pragma("unroll")                                                         \
    for (int r = 0; r < 4; ++r) {                                             \
      float v = sc[r];                                                        \
      v += __shfl_xor(v, 1, 16); v += __shfl_xor(v, 2, 16);                   \
      v += __shfl_xor(v, 4, 16); v += __shfl_xor(v, 8, 16);                   \
      if (l15 == 0) scores[((MT) - mt0) * 16 + g * 4 + r] = v;                \
    }                                                                         \
  } while (0)

  TILE_SCORE(mt0 + wv);
  if (wv + 4 < NT) TILE_SCORE(mt0 + 4 + wv);
#undef TILE_SCORE
  __syncthreads();   // barrier 2

  // ---- phase B: LOCAL masked softmax over this half's L rows.
  float mloc, Zloc;
  {
    float s = (tid < L && mk) ? scores[tid] : -INFINITY;
    float v = s;
    #pragma unroll
    for (int m = 32; m >= 1; m >>= 1) v = fmaxf(v, __shfl_xor(v, m, 64));
    if (lane == 0) red[wv] = v;
    __syncthreads();   // barrier 3
    mloc = fmaxf(fmaxf(red[0], red[1]), fmaxf(red[2], red[3]));
    float e = (tid < L && mk) ? __expf(s - mloc) : 0.f;
    float sv = e;
    #pragma unroll
    for (int m = 32; m >= 1; m >>= 1) sv += __shfl_xor(sv, m, 64);
    if (lane == 0) red[4 + wv] = sv;
    if (tid < L) scores[tid] = e;   // unnormalized (0 for masked/clamped rows)
    __syncthreads();   // barrier 4; wbt dead -> part alias OK
    Zloc = (red[4] + red[5]) + (red[6] + red[7]);
  }

  // ---- phase C: O_half partials over this half's rows (L2/L3-hot re-read).
  // Row addresses CLAMPED to 199: rows >=200 have e==0, clamped value unused.
  {
    const int d4 = (tid & 31) << 2;
    const int p  = tid >> 5;            // 0..7
    const int nt = L >> 3;              // 14 or 12 t's per p
    const float* xb = x + (size_t)b * B_T * B_D + d4;
    f32x4 acc0 = {0.f, 0.f, 0.f, 0.f}, acc1 = {0.f, 0.f, 0.f, 0.f};
    #pragma unroll 6
    for (int t = 0; t < nt; t += 2) {
      int r0 = rbase + p * nt + t;     if (r0 > B_T - 1) r0 = B_T - 1;
      int r1 = rbase + p * nt + t + 1; if (r1 > B_T - 1) r1 = B_T - 1;
      f32x4 xv0 = *(const f32x4*)(xb + (size_t)r0 * B_D);
      f32x4 xv1 = *(const f32x4*)(xb + (size_t)r1 * B_D);
      float w0 = scores[p * nt + t];
      float w1 = scores[p * nt + t + 1];
      acc0[0] = fmaf(w0, xv0[0], acc0[0]); acc1[0] = fmaf(w1, xv1[0], acc1[0]);
      acc0[1] = fmaf(w0, xv0[1], acc0[1]); acc1[1] = fmaf(w1, xv1[1], acc1[1]);
      acc0[2] = fmaf(w0, xv0[2], acc0[2]); acc1[2] = fmaf(w1, xv1[2], acc1[2]);
      acc0[3] = fmaf(w0, xv0[3], acc0[3]); acc1[3] = fmaf(w1, xv1[3], acc1[3]);
    }
    acc0[0] += acc1[0]; acc0[1] += acc1[1]; acc0[2] += acc1[2]; acc0[3] += acc1[3];
    *(f32x4*)&part[p][d4] = acc0;
  }
  __syncthreads();   // barrier 5
  if (tid < B_D) {
    float s = 0.f;
    #pragma unroll
    for (int p = 0; p < 8; ++p) s += part[p][tid];
    wsO[(size_t)bi * B_D + tid] = s;
  }
  if (tid == 0) { wsMZ[bi * 2] = mloc; wsMZ[bi * 2 + 1] = Zloc; }
}

// Kernel 2: flash combine of the two halves (exact).
__global__ __launch_bounds__(128)
void ta_combine(const float* __restrict__ wsO, const float* __restrict__ wsMZ,
                float* __restrict__ out) {
  const int b = blockIdx.x, d = threadIdx.x;
  const float m1 = wsMZ[(b * 2    ) * 2], Z1 = wsMZ[(b * 2    ) * 2 + 1];
  const float m2 = wsMZ[(b * 2 + 1) * 2], Z2 = wsMZ[(b * 2 + 1) * 2 + 1];
  const float m  = fmaxf(m1, m2);
  const float f1 = (Z1 > 0.f) ? __expf(m1 - m) : 0.f;
  const float f2 = (Z2 > 0.f) ? __expf(m2 - m) : 0.f;
  const float Z  = f1 * Z1 + f2 * Z2;
  const float o1 = wsO[(size_t)(b * 2) * B_D + d];
  const float o2 = wsO[(size_t)(b * 2 + 1) * B_D + d];
  out[(size_t)b * B_D + d] = (f1 * o1 + f2 * o2) / Z;
}

extern "C" void kernel_launch(void* const* d_in, const int* in_sizes, int n_in,
                              void* d_out, int out_size, void* d_ws, size_t ws_size,
                              hipStream_t stream) {
  const float* x    = (const float*)d_in[0];
  const float* cand = (const float*)d_in[1];
  const void*  mask = d_in[2];
  const float* W1   = (const float*)d_in[3];
  const float* b1   = (const float*)d_in[4];
  const float* a    = (const float*)d_in[5];
  const float* W2   = (const float*)d_in[6];
  float* out = (float*)d_out;
  const int B = in_sizes[1] / B_D;   // candidate is [B,128]

  float* wsO  = (float*)d_ws;                                    // [B*2][128]
  float* wsMZ = (float*)((char*)d_ws + (size_t)B * 2 * B_D * 4); // [B*2][2]

  ta_half<<<B * 2, 256, 0, stream>>>(x, cand, mask, W1, b1, a, W2, wsO, wsMZ);
  ta_combine<<<B, 128, 0, stream>>>(wsO, wsMZ, out);
}